// Round 1
// baseline (686.182 us; speedup 1.0000x reference)
//
#include <hip/hip_runtime.h>
#include <hip/hip_bf16.h>

#define NVERT 40962
#define NFACE 81920
#define NB 16
#define NC 32
#define NO 32
#define BC 512   // NB*NC

// ---------- bf16 pack/unpack (RNE, manual to avoid API ambiguity) ----------
__device__ __forceinline__ unsigned int packbf2(float a, float b) {
  unsigned int ua = __float_as_uint(a);
  ua = ua + 0x7fffu + ((ua >> 16) & 1u);
  unsigned int ub = __float_as_uint(b);
  ub = ub + 0x7fffu + ((ub >> 16) & 1u);
  return (ua >> 16) | (ub & 0xffff0000u);
}

__device__ __forceinline__ float2 unpackbf2(unsigned int u) {
  float2 r;
  r.x = __uint_as_float(u << 16);
  r.y = __uint_as_float(u & 0xffff0000u);
  return r;
}

// ---------- K0: transpose x[512, NV] f32 -> xT[NV, 512] bf16 (packed u32) ----
__global__ __launch_bounds__(256) void k_transpose(const float* __restrict__ x,
                                                   unsigned int* __restrict__ xT) {
  __shared__ float tile[32][33];
  int n0 = blockIdx.x * 32;
  int r0 = blockIdx.y * 32;            // bc-row base
  int tx = threadIdx.x & 31;
  int ty = threadIdx.x >> 5;           // 0..7
#pragma unroll
  for (int i = 0; i < 32; i += 8) {
    int n = n0 + tx;
    tile[ty + i][tx] = (n < NVERT) ? x[(size_t)(r0 + ty + i) * NVERT + n] : 0.f;
  }
  __syncthreads();
#pragma unroll
  for (int i = 0; i < 32; i += 16) {
    int nl = (threadIdx.x >> 4) + i;   // 0..31 over two passes
    int u  = threadIdx.x & 15;         // packed-uint index within 32 bc
    int n  = n0 + nl;
    if (n < NVERT)
      xT[(size_t)n * 256 + (r0 >> 1) + u] = packbf2(tile[2 * u][nl], tile[2 * u + 1][nl]);
  }
}

// ---------- K1: per-face grad + EW/NS projection -> gfew/gfns [NF,512] bf16 --
__global__ __launch_bounds__(256) void k_faces(
    const unsigned int* __restrict__ xT,
    const int* __restrict__ Gc, const float* __restrict__ Gv,
    const float* __restrict__ EW, const float* __restrict__ NS,
    unsigned int* __restrict__ gfew, unsigned int* __restrict__ gfns) {
  int f = blockIdx.x;
  int t = threadIdx.x;                 // handles bc = 2t, 2t+1
  float e0 = 0.f, e1 = 0.f, s0 = 0.f, s1 = 0.f;
#pragma unroll
  for (int comp = 0; comp < 3; ++comp) {
    int base = comp * (3 * NFACE) + 3 * f;   // nnz base of row comp*NF+f
    float g0 = 0.f, g1 = 0.f;
#pragma unroll
    for (int j = 0; j < 3; ++j) {
      int col = Gc[base + j];
      float v = Gv[base + j];
      float2 xv = unpackbf2(xT[(size_t)col * 256 + t]);
      g0 = fmaf(v, xv.x, g0);
      g1 = fmaf(v, xv.y, g1);
    }
    float ew = EW[3 * f + comp], ns = NS[3 * f + comp];
    e0 = fmaf(ew, g0, e0); e1 = fmaf(ew, g1, e1);
    s0 = fmaf(ns, g0, s0); s1 = fmaf(ns, g1, s1);
  }
  gfew[(size_t)f * 256 + t] = packbf2(e0, e1);
  gfns[(size_t)f * 256 + t] = packbf2(s0, s1);
}

// ---------- K2: per-vertex features + channel-mix combine -------------------
__global__ __launch_bounds__(256) void k_verts(
    const unsigned int* __restrict__ xT,
    const int* __restrict__ Lc, const float* __restrict__ Lv,
    const int* __restrict__ Fc, const float* __restrict__ Fv,
    const unsigned int* __restrict__ gfew, const unsigned int* __restrict__ gfns,
    const float* __restrict__ coeffs, const float* __restrict__ bias,
    float* __restrict__ out) {
  __shared__ float featS[16][132];     // [b][c*4+k], padded row
  __shared__ float Ws[4096];           // [i=c*4+k][o]
  int t = threadIdx.x;

  // bijective XCD swizzle (m204): consecutive vertices -> same XCD
  int blk = blockIdx.x;
  const int q = NVERT >> 3, r = NVERT & 7;
  int xcd = blk & 7, idx = blk >> 3;
  int n = (xcd < r ? xcd * (q + 1) : r * (q + 1) + (xcd - r) * q) + idx;

  // load W transposed: Ws[i*32+o] = coeffs[o*128+i]; contiguous LDS writes
  for (int k = t; k < 4096; k += 256) {
    int i = k >> 5, o = k & 31;
    Ws[k] = coeffs[o * 128 + i];
  }

  // ---- phase 1: build feat for bc = 2t, 2t+1 ----
  float2 idv = unpackbf2(xT[(size_t)n * 256 + t]);
  float2 lap = make_float2(0.f, 0.f);
#pragma unroll
  for (int j = 0; j < 7; ++j) {
    int col = Lc[7 * n + j];
    float v = Lv[7 * n + j];
    float2 g = unpackbf2(xT[(size_t)col * 256 + t]);
    lap.x = fmaf(v, g.x, lap.x);
    lap.y = fmaf(v, g.y, lap.y);
  }
  float2 ew = make_float2(0.f, 0.f), ns = make_float2(0.f, 0.f);
#pragma unroll
  for (int j = 0; j < 6; ++j) {
    int fc = Fc[6 * n + j];
    float v = Fv[6 * n + j];
    float2 a = unpackbf2(gfew[(size_t)fc * 256 + t]);
    float2 b = unpackbf2(gfns[(size_t)fc * 256 + t]);
    ew.x = fmaf(v, a.x, ew.x); ew.y = fmaf(v, a.y, ew.y);
    ns.x = fmaf(v, b.x, ns.x); ns.y = fmaf(v, b.y, ns.y);
  }
  int b = t >> 4;              // bc>>5
  int c0 = (2 * t) & 31;
  float4 f0 = make_float4(idv.x, lap.x, ew.x, ns.x);
  float4 f1 = make_float4(idv.y, lap.y, ew.y, ns.y);
  *reinterpret_cast<float4*>(&featS[b][c0 * 4]) = f0;
  *reinterpret_cast<float4*>(&featS[b][c0 * 4 + 4]) = f1;
  __syncthreads();

  // ---- phase 2: out[b2, o0..o0+1, n] = feat[b2,:] @ Ws[:, o0..o0+1] ----
  int b2 = t >> 4;
  int o0 = 2 * (t & 15);
  float2 bs = *reinterpret_cast<const float2*>(&bias[o0]);
  float a0 = bs.x, a1 = bs.y;
  const float* fb = featS[b2];
#pragma unroll 8
  for (int i = 0; i < 128; i += 4) {
    float4 fv = *reinterpret_cast<const float4*>(&fb[i]);
    float2 w0 = *reinterpret_cast<const float2*>(&Ws[(i + 0) * 32 + o0]);
    float2 w1 = *reinterpret_cast<const float2*>(&Ws[(i + 1) * 32 + o0]);
    float2 w2 = *reinterpret_cast<const float2*>(&Ws[(i + 2) * 32 + o0]);
    float2 w3 = *reinterpret_cast<const float2*>(&Ws[(i + 3) * 32 + o0]);
    a0 = fmaf(fv.x, w0.x, a0); a1 = fmaf(fv.x, w0.y, a1);
    a0 = fmaf(fv.y, w1.x, a0); a1 = fmaf(fv.y, w1.y, a1);
    a0 = fmaf(fv.z, w2.x, a0); a1 = fmaf(fv.z, w2.y, a1);
    a0 = fmaf(fv.w, w3.x, a0); a1 = fmaf(fv.w, w3.y, a1);
  }
  out[(size_t)(b2 * 32 + o0) * NVERT + n] = a0;
  out[(size_t)(b2 * 32 + o0 + 1) * NVERT + n] = a1;
}

extern "C" void kernel_launch(void* const* d_in, const int* in_sizes, int n_in,
                              void* d_out, int out_size, void* d_ws, size_t ws_size,
                              hipStream_t stream) {
  const float* x      = (const float*)d_in[0];
  const int*   Gc     = (const int*)  d_in[2];
  const float* Gv     = (const float*)d_in[3];
  const int*   Lc     = (const int*)  d_in[5];
  const float* Lv     = (const float*)d_in[6];
  const int*   Fc     = (const int*)  d_in[8];
  const float* Fv     = (const float*)d_in[9];
  const float* EW     = (const float*)d_in[10];
  const float* NS     = (const float*)d_in[11];
  const float* coeffs = (const float*)d_in[12];
  const float* bias   = (const float*)d_in[13];
  float* out = (float*)d_out;

  unsigned int* xT   = (unsigned int*)d_ws;            // NVERT*256 u32 (bf16x2)
  unsigned int* gfew = xT + (size_t)NVERT * 256;       // NFACE*256
  unsigned int* gfns = gfew + (size_t)NFACE * 256;     // NFACE*256

  dim3 gT((NVERT + 31) / 32, 16);
  k_transpose<<<gT, 256, 0, stream>>>(x, xT);
  k_faces<<<NFACE, 256, 0, stream>>>(xT, Gc, Gv, EW, NS, gfew, gfns);
  k_verts<<<NVERT, 256, 0, stream>>>(xT, Lc, Lv, Fc, Fv, gfew, gfns, coeffs, bias, out);
}

// Round 2
// 513.214 us; speedup vs baseline: 1.3370x; 1.3370x over previous
//
#include <hip/hip_runtime.h>
#include <hip/hip_bf16.h>

#define NVERT 40962
#define NFACE 81920
#define GRID_V ((NVERT + 3) / 4)      // 10241 blocks, 4 vertices/block (1/wave)
#define GRID_F (NFACE / 4)            // 20480 blocks, 4 faces/block (1/wave)

typedef unsigned int uint;
typedef __attribute__((ext_vector_type(4))) uint  uintx4;
typedef __attribute__((ext_vector_type(4))) float floatx4;
typedef __attribute__((ext_vector_type(8))) short shortx8;

// ---------- bf16 helpers (RNE) ----------
__device__ __forceinline__ uint packbf2(float a, float b) {
  uint ua = __float_as_uint(a); ua = ua + 0x7fffu + ((ua >> 16) & 1u);
  uint ub = __float_as_uint(b); ub = ub + 0x7fffu + ((ub >> 16) & 1u);
  return (ua >> 16) | (ub & 0xffff0000u);
}
__device__ __forceinline__ float2 unpackbf2(uint u) {
  float2 r;
  r.x = __uint_as_float(u << 16);
  r.y = __uint_as_float(u & 0xffff0000u);
  return r;
}
__device__ __forceinline__ short bfr(float x) {
  uint u = __float_as_uint(x);
  u = u + 0x7fffu + ((u >> 16) & 1u);
  return (short)(u >> 16);
}

// bijective XCD swizzle (m204)
__device__ __forceinline__ int swz(int blk, int nwg) {
  int q = nwg >> 3, r = nwg & 7;
  int xcd = blk & 7, idx = blk >> 3;
  return (xcd < r ? xcd * (q + 1) : r * (q + 1) + (xcd - r) * q) + idx;
}

// ---------- K0: transpose x[512,NV] f32 -> xT[NV,256] u32 (bf16x2), permuted --
// word order: position u' = (u&3)*64 + (u>>4)*4 + ((u>>2)&3), where word u
// holds bc pair (2u, 2u+1). This makes lane l's dwordx4 (words 4l..4l+3)
// deliver exactly its MFMA A-fragment k-slices (b=l&15, kgroup=l>>4, ks=0..3).
__global__ __launch_bounds__(256) void k_transpose(const float* __restrict__ x,
                                                   uint* __restrict__ xT) {
  __shared__ float tile[32][33];
  int n0 = blockIdx.x * 32;
  int r0 = blockIdx.y * 32;
  int tx = threadIdx.x & 31;
  int ty = threadIdx.x >> 5;
#pragma unroll
  for (int i = 0; i < 32; i += 8) {
    int n = n0 + tx;
    tile[ty + i][tx] = (n < NVERT) ? x[(size_t)(r0 + ty + i) * NVERT + n] : 0.f;
  }
  __syncthreads();
#pragma unroll
  for (int i = 0; i < 32; i += 16) {
    int nl = (threadIdx.x >> 4) + i;
    int u  = threadIdx.x & 15;
    int n  = n0 + nl;
    int ug = 16 * blockIdx.y + u;                       // global word index
    int up = (ug & 3) * 64 + (ug >> 4) * 4 + ((ug >> 2) & 3);
    if (n < NVERT)
      xT[(size_t)n * 256 + up] = packbf2(tile[2 * u][nl], tile[2 * u + 1][nl]);
  }
}

// ---------- K1: one wave per face: grad + EW/NS projection -> gf[NF][512] ----
// gf row: words 0..255 = ew (permuted order), 256..511 = ns
__global__ __launch_bounds__(256) void k_faces(
    const uint* __restrict__ xT,
    const int* __restrict__ Gc, const float* __restrict__ Gv,
    const float* __restrict__ EW, const float* __restrict__ NS,
    uint* __restrict__ gf) {
  const int t = threadIdx.x, lane = t & 63, wid = t >> 6;
  int f = swz(blockIdx.x, GRID_F) * 4 + wid;

  float gr[3][4][2];
#pragma unroll
  for (int c = 0; c < 3; ++c)
#pragma unroll
    for (int ks = 0; ks < 4; ++ks) { gr[c][ks][0] = 0.f; gr[c][ks][1] = 0.f; }

#pragma unroll
  for (int comp = 0; comp < 3; ++comp) {
    int base = comp * (3 * NFACE) + 3 * f;
#pragma unroll
    for (int j = 0; j < 3; ++j) {
      int col = Gc[base + j];
      float v = Gv[base + j];
      uintx4 g = *(const uintx4*)(xT + (size_t)col * 256 + 4 * lane);
#pragma unroll
      for (int ks = 0; ks < 4; ++ks) {
        float2 p = unpackbf2(g[ks]);
        gr[comp][ks][0] = fmaf(v, p.x, gr[comp][ks][0]);
        gr[comp][ks][1] = fmaf(v, p.y, gr[comp][ks][1]);
      }
    }
  }
  float e0 = EW[3 * f], e1 = EW[3 * f + 1], e2 = EW[3 * f + 2];
  float s0 = NS[3 * f], s1 = NS[3 * f + 1], s2 = NS[3 * f + 2];
  uintx4 we, wn;
#pragma unroll
  for (int ks = 0; ks < 4; ++ks) {
    float ex = fmaf(e2, gr[2][ks][0], fmaf(e1, gr[1][ks][0], e0 * gr[0][ks][0]));
    float ey = fmaf(e2, gr[2][ks][1], fmaf(e1, gr[1][ks][1], e0 * gr[0][ks][1]));
    float sx = fmaf(s2, gr[2][ks][0], fmaf(s1, gr[1][ks][0], s0 * gr[0][ks][0]));
    float sy = fmaf(s2, gr[2][ks][1], fmaf(s1, gr[1][ks][1], s0 * gr[0][ks][1]));
    we[ks] = packbf2(ex, ey);
    wn[ks] = packbf2(sx, sy);
  }
  uint* op = gf + (size_t)f * 512 + 4 * lane;
  *(uintx4*)op         = we;
  *(uintx4*)(op + 256) = wn;
}

// ---------- K2: one wave per vertex: features in regs -> MFMA channel mix ----
__global__ __launch_bounds__(256) void k_verts(
    const uint* __restrict__ xT,
    const int* __restrict__ Lc, const float* __restrict__ Lv,
    const int* __restrict__ Fc, const float* __restrict__ Fv,
    const uint* __restrict__ gf,
    const float* __restrict__ coeffs, const float* __restrict__ bias,
    float* __restrict__ out) {
  const int t = threadIdx.x, lane = t & 63, wid = t >> 6;
  int n = swz(blockIdx.x, GRID_V) * 4 + wid;
  if (n >= NVERT) return;
  const int h = lane >> 4, bm = lane & 15;

  // identity gather (this vertex's own row)
  uintx4 idw = *(const uintx4*)(xT + (size_t)n * 256 + 4 * lane);

  float lap[4][2], ewa[4][2], nsa[4][2];
#pragma unroll
  for (int ks = 0; ks < 4; ++ks) {
    lap[ks][0] = 0.f; lap[ks][1] = 0.f;
    ewa[ks][0] = 0.f; ewa[ks][1] = 0.f;
    nsa[ks][0] = 0.f; nsa[ks][1] = 0.f;
  }

  // Laplacian: 7 gathered rows
#pragma unroll
  for (int j = 0; j < 7; ++j) {
    int col = Lc[7 * n + j];
    float v = Lv[7 * n + j];
    uintx4 g = *(const uintx4*)(xT + (size_t)col * 256 + 4 * lane);
#pragma unroll
    for (int ks = 0; ks < 4; ++ks) {
      float2 p = unpackbf2(g[ks]);
      lap[ks][0] = fmaf(v, p.x, lap[ks][0]);
      lap[ks][1] = fmaf(v, p.y, lap[ks][1]);
    }
  }
  // F2V: 6 faces, ew+ns interleaved rows
#pragma unroll
  for (int j = 0; j < 6; ++j) {
    int fc = Fc[6 * n + j];
    float v = Fv[6 * n + j];
    const uint* rp = gf + (size_t)fc * 512 + 4 * lane;
    uintx4 ge = *(const uintx4*)rp;
    uintx4 gn = *(const uintx4*)(rp + 256);
#pragma unroll
    for (int ks = 0; ks < 4; ++ks) {
      float2 a = unpackbf2(ge[ks]);
      float2 b = unpackbf2(gn[ks]);
      ewa[ks][0] = fmaf(v, a.x, ewa[ks][0]); ewa[ks][1] = fmaf(v, a.y, ewa[ks][1]);
      nsa[ks][0] = fmaf(v, b.x, nsa[ks][0]); nsa[ks][1] = fmaf(v, b.y, nsa[ks][1]);
    }
  }

  // A-fragments: e = {id,lap,ew,ns}(even c), {id,lap,ew,ns}(odd c)
  shortx8 afr[4];
#pragma unroll
  for (int ks = 0; ks < 4; ++ks) {
    float2 ip = unpackbf2(idw[ks]);
    shortx8 a;
    a[0] = bfr(ip.x);       a[1] = bfr(lap[ks][0]);
    a[2] = bfr(ewa[ks][0]); a[3] = bfr(nsa[ks][0]);
    a[4] = bfr(ip.y);       a[5] = bfr(lap[ks][1]);
    a[6] = bfr(ewa[ks][1]); a[7] = bfr(nsa[ks][1]);
    afr[ks] = a;
  }

  // B-fragments from coeffs (W[k][o] = coeffs[o*128+k]); C init = bias
  float b0 = bias[bm], b1 = bias[16 + bm];
  floatx4 acc0 = {b0, b0, b0, b0};
  floatx4 acc1 = {b1, b1, b1, b1};

#pragma unroll
  for (int ks = 0; ks < 4; ++ks) {
    const float* wp0 = coeffs + (size_t)bm * 128 + 32 * ks + 8 * h;
    floatx4 w0 = *(const floatx4*)wp0;
    floatx4 w1 = *(const floatx4*)(wp0 + 4);
    shortx8 bf0;
    bf0[0] = bfr(w0[0]); bf0[1] = bfr(w0[1]); bf0[2] = bfr(w0[2]); bf0[3] = bfr(w0[3]);
    bf0[4] = bfr(w1[0]); bf0[5] = bfr(w1[1]); bf0[6] = bfr(w1[2]); bf0[7] = bfr(w1[3]);
    acc0 = __builtin_amdgcn_mfma_f32_16x16x32_bf16(afr[ks], bf0, acc0, 0, 0, 0);

    const float* wp1 = wp0 + 16 * 128;
    floatx4 w2 = *(const floatx4*)wp1;
    floatx4 w3 = *(const floatx4*)(wp1 + 4);
    shortx8 bf1;
    bf1[0] = bfr(w2[0]); bf1[1] = bfr(w2[1]); bf1[2] = bfr(w2[2]); bf1[3] = bfr(w2[3]);
    bf1[4] = bfr(w3[0]); bf1[5] = bfr(w3[1]); bf1[6] = bfr(w3[2]); bf1[7] = bfr(w3[3]);
    acc1 = __builtin_amdgcn_mfma_f32_16x16x32_bf16(afr[ks], bf1, acc1, 0, 0, 0);
  }

  // C/D layout: col = lane&15 (=o within tile), row = (lane>>4)*4+reg (=b)
#pragma unroll
  for (int reg = 0; reg < 4; ++reg) {
    int b = h * 4 + reg;
    out[(size_t)(b * 32 + bm) * NVERT + n]      = acc0[reg];
    out[(size_t)(b * 32 + 16 + bm) * NVERT + n] = acc1[reg];
  }
}

extern "C" void kernel_launch(void* const* d_in, const int* in_sizes, int n_in,
                              void* d_out, int out_size, void* d_ws, size_t ws_size,
                              hipStream_t stream) {
  const float* x      = (const float*)d_in[0];
  const int*   Gc     = (const int*)  d_in[2];
  const float* Gv     = (const float*)d_in[3];
  const int*   Lc     = (const int*)  d_in[5];
  const float* Lv     = (const float*)d_in[6];
  const int*   Fc     = (const int*)  d_in[8];
  const float* Fv     = (const float*)d_in[9];
  const float* EW     = (const float*)d_in[10];
  const float* NS     = (const float*)d_in[11];
  const float* coeffs = (const float*)d_in[12];
  const float* bias   = (const float*)d_in[13];
  float* out = (float*)d_out;

  uint* xT = (uint*)d_ws;                       // NVERT*256 u32
  uint* gf = xT + (size_t)NVERT * 256;          // NFACE*512 u32 (ew|ns)

  dim3 gT((NVERT + 31) / 32, 16);
  k_transpose<<<gT, 256, 0, stream>>>(x, xT);
  k_faces<<<GRID_F, 256, 0, stream>>>(xT, Gc, Gv, EW, NS, gf);
  k_verts<<<GRID_V, 256, 0, stream>>>(xT, Lc, Lv, Fc, Fv, gf, coeffs, bias, out);
}